// Round 14
// baseline (724.928 us; speedup 1.0000x reference)
//
#include <hip/hip_runtime.h>

#define N_NODES 100000
#define NEDGE   1600000
#define D       32

#define BSHIFT   8
#define BNODES   256                                  // nodes per bucket
#define NBUCKET  ((N_NODES + BNODES - 1) / BNODES)    // 391
#define NB_PAD   392
#define EPB      4096                                 // edges per block in bin pass
#define EPT      (EPB / 256)                          // 16 edges per thread
#define CBLK     ((NEDGE + EPB - 1) / EPB)            // 391
#define CAP      5120                                 // arena slots per bucket (mean 4096, sd~64 -> 16 sigma)
#define ASTRIDE  33                                   // padded LDS acc stride (floats)

// ---------- Kernel C: bin edges into fixed arenas, coalesced write-out ----------
// packed: x = src | (dst_local << 17)   (src < 2^17, dst_local < 256), y = w bits
// cur[] is RELATIVE (memset-0 seeded); arena base b*CAP added at use.
__global__ __launch_bounds__(256) void bin_edges_kernel(
        const int* __restrict__ src, const int* __restrict__ dst,
        const float* __restrict__ w,
        int* __restrict__ bucket_cur, int2* __restrict__ binned) {
    __shared__ int2 sorted[EPB];                 // 32 KB
    __shared__ unsigned short bucketOf[EPB];     //  8 KB
    __shared__ int cnt[NB_PAD];                  // hist, then local cursor
    __shared__ int ndoff[NB_PAD];                // local exclusive scan
    __shared__ int delta[NB_PAD];                // global_base - local_base
    __shared__ int partial[256];

    const int tid = threadIdx.x;
    const int e0  = blockIdx.x * EPB;
    const int total = min(EPB, NEDGE - e0);

    for (int i = tid; i < NB_PAD; i += 256) cnt[i] = 0;
    __syncthreads();

    // Phase 1: histogram; keep dst in statically-indexed registers
    int myd[EPT];
    #pragma unroll
    for (int it = 0; it < EPT; ++it) {
        int e = e0 + it * 256 + tid;
        myd[it] = (e < NEDGE) ? dst[e] : -1;
        if (myd[it] >= 0) atomicAdd(&cnt[myd[it] >> BSHIFT], 1);
    }
    __syncthreads();

    // Phase 2: local scan over 392 buckets (2 per thread) + global run claim
    {
        int b0 = tid * 2;
        int c0 = 0, c1 = 0, s = 0;
        if (b0 < NB_PAD) { c0 = cnt[b0]; c1 = cnt[b0 + 1]; s = c0 + c1; }
        partial[tid] = s;
        __syncthreads();
        int v = s;
        for (int o = 1; o < 256; o <<= 1) {
            int t2 = (tid >= o) ? partial[tid - o] : 0;
            __syncthreads();
            partial[tid] += t2;
            __syncthreads();
        }
        int run = partial[tid] - v;
        if (b0 < NB_PAD) {
            ndoff[b0] = run;
            if (c0 > 0) delta[b0] = b0 * CAP + atomicAdd(&bucket_cur[b0], c0) - run;
            cnt[b0] = 0;
            run += c0;
            ndoff[b0 + 1] = run;
            if (c1 > 0) delta[b0 + 1] = (b0 + 1) * CAP + atomicAdd(&bucket_cur[b0 + 1], c1) - run;
            cnt[b0 + 1] = 0;
            run += c1;
        }
    }
    __syncthreads();

    // Phase 3: scatter into LDS (coalesced src/w loads, random LDS writes)
    #pragma unroll
    for (int it = 0; it < EPT; ++it) {
        int d = myd[it];
        if (d >= 0) {
            int e = e0 + it * 256 + tid;
            int b = d >> BSHIFT;
            int r = atomicAdd(&cnt[b], 1);
            int loc = ndoff[b] + r;
            sorted[loc]   = make_int2(src[e] | ((d & (BNODES - 1)) << 17),
                                      __float_as_int(w[e]));
            bucketOf[loc] = (unsigned short)b;
        }
    }
    __syncthreads();

    // Phase 4: coalesced write-out (consecutive slots -> consecutive gaddr per run)
    for (int i = tid; i < total; i += 256) {
        int2 v = sorted[i];
        int  b = bucketOf[i];
        binned[delta[b] + i] = v;
    }
}

// ---------- Kernel E: per-bucket SpMM, edge-parallel, LDS accumulators ----------
// One block per bucket, 512 threads (8 waves), 33.8 KB LDS -> 4 blocks/CU
// (32 waves/CU, full occupancy; all 391 blocks co-resident). 8 lanes per edge
// (float4 slice each); binned reads are coalesced/broadcast, x-row gathers
// random (L2/L3), accumulation via native ds_add_f32 into acc[256][33]
// (stride 33 spreads random-dl atomics across banks). Coalesced row writes.
__global__ __launch_bounds__(512) void spmm_bucket_kernel(
        const int* __restrict__ bucket_cur, const int2* __restrict__ binned,
        const float* __restrict__ x, float* __restrict__ out) {
    __shared__ float acc[BNODES * ASTRIDE];      // 33792 B

    const int b    = blockIdx.x;
    const int tid  = threadIdx.x;
    const int start = b * CAP;
    const int cnt   = min(bucket_cur[b], CAP);

    for (int i = tid; i < BNODES * ASTRIDE; i += 512) acc[i] = 0.f;
    __syncthreads();

    const int g = tid >> 3;      // 64 edge-groups
    const int c = tid & 7;       // float4 slice within row
    int k = g;
    for (; k + 64 < cnt; k += 128) {
        int2 p0 = binned[start + k];
        int2 p1 = binned[start + k + 64];
        const float4 xv0 = *reinterpret_cast<const float4*>(&x[(long)(p0.x & 0x1FFFF) * D + c * 4]);
        const float4 xv1 = *reinterpret_cast<const float4*>(&x[(long)(p1.x & 0x1FFFF) * D + c * 4]);
        float w0 = __int_as_float(p0.y);
        float w1 = __int_as_float(p1.y);
        float* a0 = &acc[((p0.x >> 17) & (BNODES - 1)) * ASTRIDE + c * 4];
        float* a1 = &acc[((p1.x >> 17) & (BNODES - 1)) * ASTRIDE + c * 4];
        atomicAdd(a0 + 0, w0 * xv0.x);
        atomicAdd(a0 + 1, w0 * xv0.y);
        atomicAdd(a0 + 2, w0 * xv0.z);
        atomicAdd(a0 + 3, w0 * xv0.w);
        atomicAdd(a1 + 0, w1 * xv1.x);
        atomicAdd(a1 + 1, w1 * xv1.y);
        atomicAdd(a1 + 2, w1 * xv1.z);
        atomicAdd(a1 + 3, w1 * xv1.w);
    }
    if (k < cnt) {
        int2 p = binned[start + k];
        const float4 xv = *reinterpret_cast<const float4*>(&x[(long)(p.x & 0x1FFFF) * D + c * 4]);
        float wt = __int_as_float(p.y);
        float* a = &acc[((p.x >> 17) & (BNODES - 1)) * ASTRIDE + c * 4];
        atomicAdd(a + 0, wt * xv.x);
        atomicAdd(a + 1, wt * xv.y);
        atomicAdd(a + 2, wt * xv.z);
        atomicAdd(a + 3, wt * xv.w);
    }
    __syncthreads();

    const int node0 = b * BNODES;
    for (int i = tid; i < BNODES * 8; i += 512) {
        int row = i >> 3, cc = i & 7;
        int node = node0 + row;
        if (node < N_NODES) {
            const float* a = &acc[row * ASTRIDE + cc * 4];
            *reinterpret_cast<float4*>(&out[(long)node * D + cc * 4]) =
                make_float4(a[0], a[1], a[2], a[3]);
        }
    }
}

// ---------- fallback (atomic scatter) if ws too small ----------
__global__ void spmm_scatter_kernel(const int* __restrict__ src, const int* __restrict__ dst,
                                    const float* __restrict__ w, const float* __restrict__ x,
                                    float* __restrict__ out) {
    long gid = (long)blockIdx.x * blockDim.x + threadIdx.x;
    if (gid >= (long)NEDGE * 8) return;
    int e = (int)(gid >> 3);
    int c = (int)(gid & 7);
    int s = src[e], d = dst[e];
    float wt = w[e];
    const float4 xv = *reinterpret_cast<const float4*>(&x[(long)s * D + c * 4]);
    float* o = &out[(long)d * D + c * 4];
    atomicAdd(o + 0, wt * xv.x);
    atomicAdd(o + 1, wt * xv.y);
    atomicAdd(o + 2, wt * xv.z);
    atomicAdd(o + 3, wt * xv.w);
}

extern "C" void kernel_launch(void* const* d_in, const int* in_sizes, int n_in,
                              void* d_out, int out_size, void* d_ws, size_t ws_size,
                              hipStream_t stream) {
    const float* x    = (const float*)d_in[0];
    const int*   esrc = (const int*)d_in[1];
    const int*   edst = (const int*)d_in[2];
    const float* ew   = (const float*)d_in[3];
    float* out = (float*)d_out;

    char* ws = (char*)d_ws;
    const size_t y_bytes   = (size_t)N_NODES * D * sizeof(float);     // 12.8 MB
    const size_t b_ints    = (size_t)NB_PAD * sizeof(int);
    const size_t arena_sz  = (size_t)NBUCKET * CAP * sizeof(int2);    // 16.0 MB

    size_t o = 0;
    float* y          = (float*)(ws + o); o += y_bytes;
    int2*  binned     = (int2*) (ws + o); o += arena_sz;
    int*   bucket_cur = (int*)  (ws + o); o += b_ints;

    if (ws_size < o) {
        hipMemsetAsync(y, 0, y_bytes, stream);
        hipMemsetAsync(out, 0, y_bytes, stream);
        const long total = (long)NEDGE * 8;
        const int blocks = (int)((total + 255) / 256);
        spmm_scatter_kernel<<<blocks, 256, 0, stream>>>(esrc, edst, ew, x, y);
        spmm_scatter_kernel<<<blocks, 256, 0, stream>>>(esrc, edst, ew, y, out);
        return;
    }

    hipMemsetAsync(bucket_cur, 0, b_ints, stream);   // relative cursors
    bin_edges_kernel<<<CBLK, 256, 0, stream>>>(esrc, edst, ew, bucket_cur, binned);

    spmm_bucket_kernel<<<NBUCKET, 512, 0, stream>>>(bucket_cur, binned, x, y);
    spmm_bucket_kernel<<<NBUCKET, 512, 0, stream>>>(bucket_cur, binned, y, out);
}

// Round 15
// 111.759 us; speedup vs baseline: 6.4865x; 6.4865x over previous
//
#include <hip/hip_runtime.h>

#define N_NODES 100000
#define NEDGE   1600000
#define D       32

#define BSHIFT   8
#define BNODES   256                                  // nodes per bucket
#define NBUCKET  ((N_NODES + BNODES - 1) / BNODES)    // 391
#define NB_PAD   392
#define EPB      4096                                 // edges per block in bin pass
#define EPT      (EPB / 256)                          // 16 edges per thread
#define CBLK     ((NEDGE + EPB - 1) / EPB)            // 391
#define CAP      5120                                 // arena slots per bucket (mean 4096, sd~64 -> 16 sigma)

// ---------- Kernel C: bin edges into fixed arenas, coalesced write-out ----------
// packed: x = src | (dst_local << 17)   (src < 2^17, dst_local < 256), y = w bits
// cur[] is RELATIVE (memset-0 seeded); arena base b*CAP added at use.
__global__ __launch_bounds__(256) void bin_edges_kernel(
        const int* __restrict__ src, const int* __restrict__ dst,
        const float* __restrict__ w,
        int* __restrict__ bucket_cur, int2* __restrict__ binned) {
    __shared__ int2 sorted[EPB];                 // 32 KB
    __shared__ unsigned short bucketOf[EPB];     //  8 KB
    __shared__ int cnt[NB_PAD];                  // hist, then local cursor
    __shared__ int ndoff[NB_PAD];                // local exclusive scan
    __shared__ int delta[NB_PAD];                // global_base - local_base
    __shared__ int partial[256];

    const int tid = threadIdx.x;
    const int e0  = blockIdx.x * EPB;
    const int total = min(EPB, NEDGE - e0);

    for (int i = tid; i < NB_PAD; i += 256) cnt[i] = 0;
    __syncthreads();

    // Phase 1: histogram; keep dst in statically-indexed registers
    int myd[EPT];
    #pragma unroll
    for (int it = 0; it < EPT; ++it) {
        int e = e0 + it * 256 + tid;
        myd[it] = (e < NEDGE) ? dst[e] : -1;
        if (myd[it] >= 0) atomicAdd(&cnt[myd[it] >> BSHIFT], 1);
    }
    __syncthreads();

    // Phase 2: local scan over 392 buckets (2 per thread) + global run claim
    {
        int b0 = tid * 2;
        int c0 = 0, c1 = 0, s = 0;
        if (b0 < NB_PAD) { c0 = cnt[b0]; c1 = cnt[b0 + 1]; s = c0 + c1; }
        partial[tid] = s;
        __syncthreads();
        int v = s;
        for (int o = 1; o < 256; o <<= 1) {
            int t2 = (tid >= o) ? partial[tid - o] : 0;
            __syncthreads();
            partial[tid] += t2;
            __syncthreads();
        }
        int run = partial[tid] - v;
        if (b0 < NB_PAD) {
            ndoff[b0] = run;
            if (c0 > 0) delta[b0] = b0 * CAP + atomicAdd(&bucket_cur[b0], c0) - run;
            cnt[b0] = 0;
            run += c0;
            ndoff[b0 + 1] = run;
            if (c1 > 0) delta[b0 + 1] = (b0 + 1) * CAP + atomicAdd(&bucket_cur[b0 + 1], c1) - run;
            cnt[b0 + 1] = 0;
            run += c1;
        }
    }
    __syncthreads();

    // Phase 3: scatter into LDS (coalesced src/w loads, random LDS writes)
    #pragma unroll
    for (int it = 0; it < EPT; ++it) {
        int d = myd[it];
        if (d >= 0) {
            int e = e0 + it * 256 + tid;
            int b = d >> BSHIFT;
            int r = atomicAdd(&cnt[b], 1);
            int loc = ndoff[b] + r;
            sorted[loc]   = make_int2(src[e] | ((d & (BNODES - 1)) << 17),
                                      __float_as_int(w[e]));
            bucketOf[loc] = (unsigned short)b;
        }
    }
    __syncthreads();

    // Phase 4: coalesced write-out (consecutive slots -> consecutive gaddr per run)
    for (int i = tid; i < total; i += 256) {
        int2 v = sorted[i];
        int  b = bucketOf[i];
        binned[delta[b] + i] = v;
    }
}

// ---------- Kernel D: per-bucket CSR slice node-sort, IN PLACE ----------
// Block b owns binned[b*CAP, b*CAP+cnt) exclusively. Slice is read twice from
// global (L2-hot) to keep LDS at ~42KB (3 blocks/CU). LDS scatter then
// coalesced in-place rewrite.
__global__ __launch_bounds__(256) void build_csr_kernel(
        const int* __restrict__ bucket_cur,
        int2* __restrict__ binned, int* __restrict__ offv, int* __restrict__ deg) {
    __shared__ int2 sorted[CAP];                 // 40 KB
    __shared__ int ndcnt[BNODES];
    __shared__ int ndoff[BNODES];

    int b = blockIdx.x;
    int tid = threadIdx.x;
    int start = b * CAP;
    int cnt_b = min(bucket_cur[b], CAP);

    ndcnt[tid] = 0;
    __syncthreads();

    // node histogram (pass 1 over slice)
    for (int i = tid; i < cnt_b; i += 256)
        atomicAdd(&ndcnt[(binned[start + i].x >> 17) & (BNODES - 1)], 1);
    __syncthreads();

    // exclusive scan of 256 node counts (blockDim == BNODES == 256)
    int v = ndcnt[tid];
    ndoff[tid] = v;
    __syncthreads();
    for (int o = 1; o < BNODES; o <<= 1) {
        int t = (tid >= o) ? ndoff[tid - o] : 0;
        __syncthreads();
        ndoff[tid] += t;
        __syncthreads();
    }
    {
        int incl = ndoff[tid];
        __syncthreads();
        ndoff[tid] = incl - v;       // exclusive
        int node = b * BNODES + tid;
        if (node < N_NODES) {
            offv[node] = start + incl - v;
            deg[node]  = v;
        }
        ndcnt[tid] = 0;              // reuse as cursor
    }
    __syncthreads();

    // pass 2: scatter into LDS node-sorted, then coalesced in-place rewrite
    for (int i = tid; i < cnt_b; i += 256) {
        int2 p = binned[start + i];
        int dl = (p.x >> 17) & (BNODES - 1);
        int r = atomicAdd(&ndcnt[dl], 1);
        sorted[ndoff[dl] + r] = make_int2(p.x & 0x1FFFF, p.y);
    }
    __syncthreads();
    for (int i = tid; i < cnt_b; i += 256) binned[start + i] = sorted[i];
}

// ---------- gather SpMM (no atomics, register acc, 4-way unrolled) ----------
// 8 threads per node; each owns a float4 slice of the 32-wide feature row.
__global__ void spmm_gather_kernel(const int* __restrict__ off, const int* __restrict__ deg,
                                   const int2* __restrict__ csr_sw,
                                   const float* __restrict__ x, float* __restrict__ out) {
    int gid = blockIdx.x * blockDim.x + threadIdx.x;
    if (gid >= N_NODES * 8) return;
    int node = gid >> 3;
    int c    = gid & 7;
    int start = off[node];
    int len   = deg[node];
    float4 acc = {0.f, 0.f, 0.f, 0.f};
    int k = 0;
    for (; k + 4 <= len; k += 4) {
        int2 sw0 = csr_sw[start + k];
        int2 sw1 = csr_sw[start + k + 1];
        int2 sw2 = csr_sw[start + k + 2];
        int2 sw3 = csr_sw[start + k + 3];
        const float4 xv0 = *reinterpret_cast<const float4*>(&x[(long)sw0.x * D + c * 4]);
        const float4 xv1 = *reinterpret_cast<const float4*>(&x[(long)sw1.x * D + c * 4]);
        const float4 xv2 = *reinterpret_cast<const float4*>(&x[(long)sw2.x * D + c * 4]);
        const float4 xv3 = *reinterpret_cast<const float4*>(&x[(long)sw3.x * D + c * 4]);
        float w0 = __int_as_float(sw0.y), w1 = __int_as_float(sw1.y);
        float w2 = __int_as_float(sw2.y), w3 = __int_as_float(sw3.y);
        acc.x += w0 * xv0.x; acc.y += w0 * xv0.y; acc.z += w0 * xv0.z; acc.w += w0 * xv0.w;
        acc.x += w1 * xv1.x; acc.y += w1 * xv1.y; acc.z += w1 * xv1.z; acc.w += w1 * xv1.w;
        acc.x += w2 * xv2.x; acc.y += w2 * xv2.y; acc.z += w2 * xv2.z; acc.w += w2 * xv2.w;
        acc.x += w3 * xv3.x; acc.y += w3 * xv3.y; acc.z += w3 * xv3.z; acc.w += w3 * xv3.w;
    }
    for (; k < len; ++k) {
        int2 sw = csr_sw[start + k];
        const float4 xv = *reinterpret_cast<const float4*>(&x[(long)sw.x * D + c * 4]);
        float wt = __int_as_float(sw.y);
        acc.x += wt * xv.x; acc.y += wt * xv.y; acc.z += wt * xv.z; acc.w += wt * xv.w;
    }
    *reinterpret_cast<float4*>(&out[(long)node * D + c * 4]) = acc;
}

// ---------- fallback (atomic scatter) if ws too small ----------
__global__ void spmm_scatter_kernel(const int* __restrict__ src, const int* __restrict__ dst,
                                    const float* __restrict__ w, const float* __restrict__ x,
                                    float* __restrict__ out) {
    long gid = (long)blockIdx.x * blockDim.x + threadIdx.x;
    if (gid >= (long)NEDGE * 8) return;
    int e = (int)(gid >> 3);
    int c = (int)(gid & 7);
    int s = src[e], d = dst[e];
    float wt = w[e];
    const float4 xv = *reinterpret_cast<const float4*>(&x[(long)s * D + c * 4]);
    float* o = &out[(long)d * D + c * 4];
    atomicAdd(o + 0, wt * xv.x);
    atomicAdd(o + 1, wt * xv.y);
    atomicAdd(o + 2, wt * xv.z);
    atomicAdd(o + 3, wt * xv.w);
}

extern "C" void kernel_launch(void* const* d_in, const int* in_sizes, int n_in,
                              void* d_out, int out_size, void* d_ws, size_t ws_size,
                              hipStream_t stream) {
    const float* x    = (const float*)d_in[0];
    const int*   esrc = (const int*)d_in[1];
    const int*   edst = (const int*)d_in[2];
    const float* ew   = (const float*)d_in[3];
    float* out = (float*)d_out;

    char* ws = (char*)d_ws;
    const size_t y_bytes   = (size_t)N_NODES * D * sizeof(float);     // 12.8 MB
    const size_t n_ints    = (size_t)N_NODES * sizeof(int);           // 400 KB
    const size_t b_ints    = (size_t)NB_PAD * sizeof(int);
    const size_t arena_sz  = (size_t)NBUCKET * CAP * sizeof(int2);    // 16.0 MB

    size_t o = 0;
    float* y          = (float*)(ws + o); o += y_bytes;
    int2*  binned     = (int2*) (ws + o); o += arena_sz;              // CSR built in place
    int*   off        = (int*)  (ws + o); o += n_ints;
    int*   deg        = (int*)  (ws + o); o += n_ints;
    int*   bucket_cur = (int*)  (ws + o); o += b_ints;

    if (ws_size < o) {
        hipMemsetAsync(y, 0, y_bytes, stream);
        hipMemsetAsync(out, 0, y_bytes, stream);
        const long total = (long)NEDGE * 8;
        const int blocks = (int)((total + 255) / 256);
        spmm_scatter_kernel<<<blocks, 256, 0, stream>>>(esrc, edst, ew, x, y);
        spmm_scatter_kernel<<<blocks, 256, 0, stream>>>(esrc, edst, ew, y, out);
        return;
    }

    hipMemsetAsync(bucket_cur, 0, b_ints, stream);   // relative cursors: memset replaces init kernel
    bin_edges_kernel<<<CBLK, 256, 0, stream>>>(esrc, edst, ew, bucket_cur, binned);
    build_csr_kernel<<<NBUCKET, 256, 0, stream>>>(bucket_cur, binned, off, deg);

    const int gblocks = (N_NODES * 8 + 255) / 256;
    spmm_gather_kernel<<<gblocks, 256, 0, stream>>>(off, deg, binned, x, y);
    spmm_gather_kernel<<<gblocks, 256, 0, stream>>>(off, deg, binned, y, out);
}